// Round 2
// baseline (343.114 us; speedup 1.0000x reference)
//
#include <hip/hip_runtime.h>

// x: (16, 10, 512, 512) fp32. out: (16, 8, 512, 512) fp32.
// Per pixel: mag = sqrt(x[8]^2 + x[9]^2); out[c] = (c == argmax(x[0..7])) ? mag : 0.
// Streaming: 167.8 MB read + 134.2 MB write, HBM floor ~48 us @ 6.3 TB/s.
// R2: nontemporal loads/stores (touch-once data, skip cache alloc) +
//     2x float4 per thread (32B/lane/channel, 20 loads in flight, 8K waves
//     = one residency pass).

typedef float f4 __attribute__((ext_vector_type(4)));

constexpr int HW    = 512 * 512;
constexpr int HW4   = HW / 4;        // 65536 float4s per (b,c) plane
constexpr int B     = 16;
constexpr int CIN   = 10;
constexpr int COUT  = 8;

__global__ __launch_bounds__(256) void HistogramLayer_52776558133573_kernel(
    const f4* __restrict__ x, f4* __restrict__ out) {
    unsigned tid = blockIdx.x * blockDim.x + threadIdx.x;  // 0 .. 524287, exact
    unsigned b   = tid >> 15;            // / (HW4/2)
    unsigned p   = (tid & 32767) << 1;   // float4 index within plane, pairs

    const f4* xb = x + (size_t)b * CIN * HW4 + p;
    f4*       ob = out + (size_t)b * COUT * HW4 + p;

    // Issue all 20 loads up front (MLP), nontemporal.
    f4 v[CIN][2];
#pragma unroll
    for (int c = 0; c < CIN; ++c) {
#pragma unroll
        for (int u = 0; u < 2; ++u)
            v[c][u] = __builtin_nontemporal_load(&xb[(size_t)c * HW4 + u]);
    }

#pragma unroll
    for (int u = 0; u < 2; ++u) {
        // argmax over channels 0..7 (strict > => first-max, matches jnp.argmax)
        f4 best = v[0][u];
        int ix = 0, iy = 0, iz = 0, iw = 0;
#pragma unroll
        for (int c = 1; c < COUT; ++c) {
            f4 t = v[c][u];
            if (t.x > best.x) { best.x = t.x; ix = c; }
            if (t.y > best.y) { best.y = t.y; iy = c; }
            if (t.z > best.z) { best.z = t.z; iz = c; }
            if (t.w > best.w) { best.w = t.w; iw = c; }
        }

        f4 g0 = v[8][u], g1 = v[9][u];
        f4 mag;
        mag.x = sqrtf(g0.x * g0.x + g1.x * g1.x);
        mag.y = sqrtf(g0.y * g0.y + g1.y * g1.y);
        mag.z = sqrtf(g0.z * g0.z + g1.z * g1.z);
        mag.w = sqrtf(g0.w * g0.w + g1.w * g1.w);

#pragma unroll
        for (int c = 0; c < COUT; ++c) {
            f4 o;
            o.x = (ix == c) ? mag.x : 0.0f;
            o.y = (iy == c) ? mag.y : 0.0f;
            o.z = (iz == c) ? mag.z : 0.0f;
            o.w = (iw == c) ? mag.w : 0.0f;
            __builtin_nontemporal_store(o, &ob[(size_t)c * HW4 + u]);
        }
    }
}

extern "C" void kernel_launch(void* const* d_in, const int* in_sizes, int n_in,
                              void* d_out, int out_size, void* d_ws, size_t ws_size,
                              hipStream_t stream) {
    const f4* x = (const f4*)d_in[0];
    f4* out = (f4*)d_out;
    const int total_threads = B * HW4 / 2;        // 524,288
    const int block = 256;
    const int grid = total_threads / block;       // 2048, exact
    HistogramLayer_52776558133573_kernel<<<grid, block, 0, stream>>>(x, out);
}

// Round 3
// 259.321 us; speedup vs baseline: 1.3231x; 1.3231x over previous
//
#include <hip/hip_runtime.h>

// x: (16, 10, 512, 512) fp32. out: (16, 8, 512, 512) fp32.
// Per pixel: mag = sqrt(x[8]^2 + x[9]^2); out[c] = (c == argmax(x[0..7])) ? mag : 0.
// Streaming: 167.8 MB read + 134.2 MB write, HBM floor ~48 us @ 6.3 TB/s.
// R3: R1 structure (1 float4/thread, plain STORES — R2's nt stores doubled
//     WRITE_SIZE to 262 MB via 32B-atom amplification and latency-choked the
//     store drain). nt kept on LOADS only (read-once, evict-first frees L2
//     for store write-combining).

typedef float f4 __attribute__((ext_vector_type(4)));

constexpr int HW   = 512 * 512;      // pixels per (b, c) plane
constexpr int HW4  = HW / 4;         // float4s per plane = 65536
constexpr int B    = 16;
constexpr int CIN  = 10;
constexpr int COUT = 8;

__global__ __launch_bounds__(256) void HistogramLayer_52776558133573_kernel(
    const f4* __restrict__ x, f4* __restrict__ out) {
    unsigned tid = blockIdx.x * blockDim.x + threadIdx.x;   // 0 .. 16*65536-1, exact
    unsigned b   = tid >> 16;          // / HW4
    unsigned hw4 = tid & (HW4 - 1);    // % HW4

    const f4* xb = x + (size_t)b * CIN * HW4 + hw4;
    f4*       ob = out + (size_t)b * COUT * HW4 + hw4;

    // All 10 loads issued up front, nontemporal (evict-first in L2).
    f4 v[CIN];
#pragma unroll
    for (int c = 0; c < CIN; ++c)
        v[c] = __builtin_nontemporal_load(&xb[(size_t)c * HW4]);

    // argmax over channels 0..7 (strict > => first-max, matches jnp.argmax)
    f4 best = v[0];
    int ix = 0, iy = 0, iz = 0, iw = 0;
#pragma unroll
    for (int c = 1; c < COUT; ++c) {
        f4 t = v[c];
        if (t.x > best.x) { best.x = t.x; ix = c; }
        if (t.y > best.y) { best.y = t.y; iy = c; }
        if (t.z > best.z) { best.z = t.z; iz = c; }
        if (t.w > best.w) { best.w = t.w; iw = c; }
    }

    f4 g0 = v[8], g1 = v[9];
    f4 mag;
    mag.x = sqrtf(g0.x * g0.x + g1.x * g1.x);
    mag.y = sqrtf(g0.y * g0.y + g1.y * g1.y);
    mag.z = sqrtf(g0.z * g0.z + g1.z * g1.z);
    mag.w = sqrtf(g0.w * g0.w + g1.w * g1.w);

    // Plain stores: full-line write-back through L2, no amplification.
#pragma unroll
    for (int c = 0; c < COUT; ++c) {
        f4 o;
        o.x = (ix == c) ? mag.x : 0.0f;
        o.y = (iy == c) ? mag.y : 0.0f;
        o.z = (iz == c) ? mag.z : 0.0f;
        o.w = (iw == c) ? mag.w : 0.0f;
        ob[(size_t)c * HW4] = o;
    }
}

extern "C" void kernel_launch(void* const* d_in, const int* in_sizes, int n_in,
                              void* d_out, int out_size, void* d_ws, size_t ws_size,
                              hipStream_t stream) {
    const f4* x = (const f4*)d_in[0];
    f4* out = (f4*)d_out;
    const int total_threads = B * HW4;            // 1,048,576
    const int block = 256;
    const int grid = total_threads / block;       // 4096, exact
    HistogramLayer_52776558133573_kernel<<<grid, block, 0, stream>>>(x, out);
}